// Round 6
// baseline (652.768 us; speedup 1.0000x reference)
//
#include <hip/hip_runtime.h>
#include <cstddef>

#define T_STEPS 24
#define F_IN 64
#define H_DIM 128
#define ROWS 96
#define NRT 6
#define TOTAL_ROWS 20800
#define NUM_BLOCKS 217   // ceil(20800 / 96); 217 <= 256 CUs -> single pass

typedef _Float16 f16;
typedef _Float16 half8 __attribute__((ext_vector_type(8)));
typedef _Float16 half4 __attribute__((ext_vector_type(4)));
typedef float floatx4 __attribute__((ext_vector_type(4)));

#define MFMA16(acc, a, b) (acc) = __builtin_amdgcn_mfma_f32_16x16x32_f16((a), (b), (acc), 0, 0, 0)

// Saturation-safe fast activations (+-inf -> correct limits, no NaN, no clamps).
__device__ __forceinline__ float sigm(float v) {
    return __builtin_amdgcn_rcpf(1.f + __builtin_amdgcn_exp2f(v * -1.44269504f));
}
__device__ __forceinline__ float tanh_(float v) {
    return 1.f - 2.f * __builtin_amdgcn_rcpf(1.f + __builtin_amdgcn_exp2f(v * 2.88539008f));
}

__global__ void cvt_f32_f16(const float* __restrict__ src, f16* __restrict__ dst, int n) {
    int i = blockIdx.x * 256 + threadIdx.x;
    if (i < n) dst[i] = (f16)src[i];
}

// 8 waves/block, 96 rows/block (6 row-tiles of 16 per wave).
// Register-budget design (round-5 -> round-6: kill the residual ~7-reg spill):
//   Persistent weights are ONLY Wgw[0] (32 regs, used in Seg3). Everything else is
//   re-loaded from global (L2-resident, 344 KB total) every step inside the segment
//   that uses it:  Seg2: Lih (24) + Lhh (48);  Seg4: Lgz (32) + Low (32).
//   An opaque `asm volatile("" : "+s"(p))` on each reload pointer defeats LICM so
//   the loads can't be hoisted back into persistent registers. Loads are issued at
//   segment top; the co-resident 2nd wave/SIMD covers the one-time L2 latency.
// Persistent ~= 32 (Wgw0) + 48 (h0p,h1p) + ~27 misc ~= 107; worst peak ~220 < 256.
// Two barriers/step: Seg2 | B2 | Seg3 | B3 | Seg4 -> Seg2(t+1).
__global__ __launch_bounds__(512, 2) void gru_fused(
    const float* __restrict__ x,
    const float* __restrict__ b_ih, const float* __restrict__ b_hh,
    const float* __restrict__ gate_b, const float* __restrict__ out_b,
    const f16* __restrict__ wih, const f16* __restrict__ whh,
    const f16* __restrict__ gw, const f16* __restrict__ ow,
    float* __restrict__ out)
{
    __shared__ f16 sX[ROWS][72];       // x_t tile (written for t+1 at end of Seg3)
    __shared__ f16 sH0a[ROWS][136];    // h0 double buffer
    __shared__ f16 sH0b[ROWS][136];
    __shared__ f16 sH1a[ROWS][136];    // h1 double buffer
    __shared__ f16 sH1b[ROWS][136];
    __shared__ f16 sRH[ROWS][136];     // r * h1_old

    const int tid  = threadIdx.x;
    const int lane = tid & 63;
    const int wv   = tid >> 6;      // 0..7 -> column tile
    const int p    = lane & 15;     // col-in-tile (B frag) / row-in-tile (A frag)
    const int quad = lane >> 4;     // 0..3
    const int ko   = quad * 8;      // k-offset within a K=32 chunk
    const int c    = wv * 16 + p;   // global output column 0..127
    const int row0 = blockIdx.x * ROWS;
    const bool full = (row0 + ROWS) <= TOTAL_ROWS;

    // x staging geometry: 512 threads x 3 passes of float4 -> 96 rows x 64 floats
    const int xr  = tid >> 4;          // 0..31
    const int xc  = (tid & 15) * 4;    // 0..60
    const int xrg = row0 + xr;

    // zero-init state buffers read at t=0
    for (int i = tid; i < (ROWS * 136) / 2; i += 512) {
        ((unsigned int*)&sH0a[0][0])[i] = 0u;
        ((unsigned int*)&sH1a[0][0])[i] = 0u;
    }

    // per-column biases
    const float bR  = b_ih[c] + b_hh[c];
    const float bZ  = b_ih[128 + c] + b_hh[128 + c];
    const float bIN = b_ih[256 + c];
    const float bHN = b_hh[256 + c];
    const float bGR = gate_b[c];
    const float bGZ = gate_b[128 + c];
    const float bO  = out_b[c];

    // ---- persistent weight fragments: ONLY Wgw[0] (gR gate, used in Seg3) ----
    half8 Wgw0[8];
    #pragma unroll
    for (int kc = 0; kc < 8; ++kc)
        Wgw0[kc] = *(const half8*)(gw + (size_t)c * 256 + kc * 32 + ko);

    // opaque weight pointers for the per-step reloads (asm defeats LICM)
    const f16* wih_v = wih;
    const f16* whh_v = whh;
    const f16* gw_v  = gw;
    const f16* ow_v  = ow;

    // recurrent state, fp32 regs: element i -> row rt*16 + quad*4 + i, col c
    floatx4 h0p[NRT], h1p[NRT];
    #pragma unroll
    for (int rt = 0; rt < NRT; ++rt) {
        h0p[rt] = (floatx4){0.f, 0.f, 0.f, 0.f};
        h1p[rt] = (floatx4){0.f, 0.f, 0.f, 0.f};
    }

    // stage x(t=0)
    {
        #pragma unroll
        for (int pp = 0; pp < 3; ++pp) {
            int gr = xrg + 32 * pp;
            if (gr > TOTAL_ROWS - 1) gr = TOTAL_ROWS - 1;
            const floatx4 v = *(const floatx4*)(x + (size_t)gr * (T_STEPS * F_IN) + xc);
            half4 h; h[0] = (f16)v[0]; h[1] = (f16)v[1]; h[2] = (f16)v[2]; h[3] = (f16)v[3];
            *(half4*)&sX[xr + 32 * pp][xc] = h;
        }
    }
    __syncthreads();

    for (int t = 0; t < T_STEPS; ++t) {
        const f16 (*sH0r)[136] = (t & 1) ? sH0b : sH0a;  // old h0
        f16 (*sH0w)[136]       = (t & 1) ? sH0a : sH0b;  // new h0
        const f16 (*sH1r)[136] = (t & 1) ? sH1b : sH1a;  // old h1
        f16 (*sH1w)[136]       = (t & 1) ? sH1a : sH1b;  // new h1

        // ---- Seg2: layer-0 GRUCell (Whh + Wih reloaded per step, L2-hit) ----
        asm volatile("" : "+s"(whh_v));
        asm volatile("" : "+s"(wih_v));
        half8 Lhh[3][4], Lih[3][2];
        #pragma unroll
        for (int g = 0; g < 3; ++g)
            #pragma unroll
            for (int kc = 0; kc < 4; ++kc)
                Lhh[g][kc] = *(const half8*)(whh_v + (size_t)(g * 128 + c) * 128 + kc * 32 + ko);
        #pragma unroll
        for (int g = 0; g < 3; ++g)
            #pragma unroll
            for (int kc = 0; kc < 2; ++kc)
                Lih[g][kc] = *(const half8*)(wih_v + (size_t)(g * 128 + c) * 64 + kc * 32 + ko);
        #pragma unroll
        for (int rt = 0; rt < NRT; ++rt) {
            floatx4 aR = (floatx4){0.f, 0.f, 0.f, 0.f};
            floatx4 aZ = aR, aIN = aR, aHN = aR;
            #pragma unroll
            for (int kc = 0; kc < 4; ++kc) {
                const half8 ah = *(const half8*)&sH0r[rt * 16 + p][kc * 32 + ko];
                MFMA16(aR,  ah, Lhh[0][kc]);
                MFMA16(aZ,  ah, Lhh[1][kc]);
                MFMA16(aHN, ah, Lhh[2][kc]);
            }
            #pragma unroll
            for (int kc = 0; kc < 2; ++kc) {
                const half8 ax = *(const half8*)&sX[rt * 16 + p][kc * 32 + ko];
                MFMA16(aR,  ax, Lih[0][kc]);
                MFMA16(aZ,  ax, Lih[1][kc]);
                MFMA16(aIN, ax, Lih[2][kc]);
            }
            #pragma unroll
            for (int i = 0; i < 4; ++i) {
                const float r  = sigm(aR[i] + bR);
                const float z  = sigm(aZ[i] + bZ);
                const float n  = tanh_(aIN[i] + bIN + r * (aHN[i] + bHN));
                const float h0 = n + z * (h0p[rt][i] - n);
                h0p[rt][i] = h0;
                sH0w[rt * 16 + quad * 4 + i][c] = (f16)h0;
            }
        }
        __syncthreads();   // B2: h0new visible; orders Seg4(t-1) sH1w-writes vs Seg3 reads
                           //     and Seg4(t-1) sRH-reads vs Seg3 writes

        // ---- Seg3: issue x(t+1) loads; gR GEMM (persistent Wgw0); write sRH; store x ----
        floatx4 px0, px1, px2;
        if (t < T_STEPS - 1) {
            const float* xb = x + (size_t)(t + 1) * F_IN + xc;
            int g0 = xrg;       if (g0 > TOTAL_ROWS - 1) g0 = TOTAL_ROWS - 1;
            int g1 = xrg + 32;  if (g1 > TOTAL_ROWS - 1) g1 = TOTAL_ROWS - 1;
            int g2 = xrg + 64;  if (g2 > TOTAL_ROWS - 1) g2 = TOTAL_ROWS - 1;
            px0 = *(const floatx4*)(xb + (size_t)g0 * (T_STEPS * F_IN));
            px1 = *(const floatx4*)(xb + (size_t)g1 * (T_STEPS * F_IN));
            px2 = *(const floatx4*)(xb + (size_t)g2 * (T_STEPS * F_IN));
        }
        #pragma unroll
        for (int rt = 0; rt < NRT; ++rt) {
            floatx4 gR = (floatx4){0.f, 0.f, 0.f, 0.f};
            #pragma unroll
            for (int kc = 0; kc < 4; ++kc) {
                const half8 a1 = *(const half8*)&sH1r[rt * 16 + p][kc * 32 + ko];
                MFMA16(gR, a1, Wgw0[4 + kc]);
            }
            #pragma unroll
            for (int kc = 0; kc < 4; ++kc) {
                const half8 a0 = *(const half8*)&sH0w[rt * 16 + p][kc * 32 + ko];
                MFMA16(gR, a0, Wgw0[kc]);
            }
            #pragma unroll
            for (int i = 0; i < 4; ++i) {
                const float r1 = sigm(gR[i] + bGR);
                sRH[rt * 16 + quad * 4 + i][c] = (f16)(r1 * h1p[rt][i]);
            }
        }
        if (t < T_STEPS - 1) {
            half4 h;
            h[0] = (f16)px0[0]; h[1] = (f16)px0[1]; h[2] = (f16)px0[2]; h[3] = (f16)px0[3];
            *(half4*)&sX[xr][xc] = h;
            h[0] = (f16)px1[0]; h[1] = (f16)px1[1]; h[2] = (f16)px1[2]; h[3] = (f16)px1[3];
            *(half4*)&sX[xr + 32][xc] = h;
            h[0] = (f16)px2[0]; h[1] = (f16)px2[1]; h[2] = (f16)px2[2]; h[3] = (f16)px2[3];
            *(half4*)&sX[xr + 64][xc] = h;
        }
        __syncthreads();   // B3: sRH and sX(t+1) visible

        // ---- Seg4: gZ GEMM + candidate GEMM (Wgw[1] + Wow reloaded per step) ----
        asm volatile("" : "+s"(gw_v));
        asm volatile("" : "+s"(ow_v));
        half8 Lgz[8], Low[8];
        #pragma unroll
        for (int kc = 0; kc < 8; ++kc)
            Lgz[kc] = *(const half8*)(gw_v + (size_t)(128 + c) * 256 + kc * 32 + ko);
        #pragma unroll
        for (int kc = 0; kc < 8; ++kc)
            Low[kc] = *(const half8*)(ow_v + (size_t)c * 256 + kc * 32 + ko);
        #pragma unroll
        for (int rt = 0; rt < NRT; ++rt) {
            floatx4 gZ = (floatx4){0.f, 0.f, 0.f, 0.f};
            floatx4 aC = gZ;
            #pragma unroll
            for (int kc = 0; kc < 4; ++kc) {
                const half8 a1 = *(const half8*)&sH1r[rt * 16 + p][kc * 32 + ko];
                MFMA16(gZ, a1, Lgz[4 + kc]);
            }
            #pragma unroll
            for (int kc = 0; kc < 4; ++kc) {
                const half8 a0 = *(const half8*)&sH0w[rt * 16 + p][kc * 32 + ko];
                MFMA16(gZ, a0, Lgz[kc]);
                MFMA16(aC, a0, Low[kc]);
            }
            #pragma unroll
            for (int kc = 0; kc < 4; ++kc) {
                const half8 ar = *(const half8*)&sRH[rt * 16 + p][kc * 32 + ko];
                MFMA16(aC, ar, Low[4 + kc]);
            }
            #pragma unroll
            for (int i = 0; i < 4; ++i) {
                const float zz = sigm(gZ[i] + bGZ);
                const float cd = tanh_(aC[i] + bO);
                const float hv = cd + zz * (h1p[rt][i] - cd);
                h1p[rt][i] = hv;
                sH1w[rt * 16 + quad * 4 + i][c] = (f16)hv;
                const int grow = row0 + rt * 16 + quad * 4 + i;
                if (full || grow < TOTAL_ROWS)
                    out[((size_t)grow * T_STEPS + t) * H_DIM + c] = hv;
            }
        }
        // no trailing barrier: B2(t+1) orders Seg4 writes/reads vs next step
    }
}

extern "C" void kernel_launch(void* const* d_in, const int* in_sizes, int n_in,
                              void* d_out, int out_size, void* d_ws, size_t ws_size,
                              hipStream_t stream) {
    (void)in_sizes; (void)n_in; (void)out_size; (void)ws_size;
    const float* x      = (const float*)d_in[0];
    const float* w_ih   = (const float*)d_in[1];
    const float* w_hh   = (const float*)d_in[2];
    const float* b_ih   = (const float*)d_in[3];
    const float* b_hh   = (const float*)d_in[4];
    const float* gate_w = (const float*)d_in[5];
    const float* gate_b = (const float*)d_in[6];
    const float* out_w  = (const float*)d_in[7];
    const float* out_b  = (const float*)d_in[8];

    f16* wsH = (f16*)d_ws;
    f16* wih = wsH;                 // 384*64   = 24576 halves
    f16* whh = wsH + 24576;         // 384*128  = 49152
    f16* gw  = wsH + 73728;         // 256*256  = 65536
    f16* ow  = wsH + 139264;        // 128*256  = 32768

    cvt_f32_f16<<<(24576 + 255) / 256, 256, 0, stream>>>(w_ih, wih, 24576);
    cvt_f32_f16<<<(49152 + 255) / 256, 256, 0, stream>>>(w_hh, whh, 49152);
    cvt_f32_f16<<<(65536 + 255) / 256, 256, 0, stream>>>(gate_w, gw, 65536);
    cvt_f32_f16<<<(32768 + 255) / 256, 256, 0, stream>>>(out_w, ow, 32768);

    gru_fused<<<NUM_BLOCKS, 512, 0, stream>>>(x, b_ih, b_hh, gate_b, out_b,
                                              wih, whh, gw, ow, (float*)d_out);
}

// Round 7
// 557.076 us; speedup vs baseline: 1.1718x; 1.1718x over previous
//
#include <hip/hip_runtime.h>
#include <cstddef>

#define T_STEPS 24
#define F_IN 64
#define H_DIM 128
#define ROWS 48
#define NRT 3
#define TOTAL_ROWS 20800
#define NUM_BLOCKS 434   // ceil(20800 / 48); last block has 16 valid rows

typedef _Float16 f16;
typedef _Float16 half8 __attribute__((ext_vector_type(8)));
typedef _Float16 half4 __attribute__((ext_vector_type(4)));
typedef float floatx4 __attribute__((ext_vector_type(4)));

#define MFMA16(acc, a, b) (acc) = __builtin_amdgcn_mfma_f32_16x16x32_f16((a), (b), (acc), 0, 0, 0)

// Saturation-safe fast activations (+-inf -> correct limits, no NaN, no clamps).
__device__ __forceinline__ float sigm(float v) {
    return __builtin_amdgcn_rcpf(1.f + __builtin_amdgcn_exp2f(v * -1.44269504f));
}
__device__ __forceinline__ float tanh_(float v) {
    return 1.f - 2.f * __builtin_amdgcn_rcpf(1.f + __builtin_amdgcn_exp2f(v * 2.88539008f));
}

__global__ void cvt_f32_f16(const float* __restrict__ src, f16* __restrict__ dst, int n) {
    int i = blockIdx.x * 256 + threadIdx.x;
    if (i < n) dst[i] = (f16)src[i];
}

// Round 7 = best-of-both: round-1's register regime (ROWS=48/NRT=3, ALL weight
// B-fragments persistent = 168 VGPR/lane, zero spill) + rounds 2-6's 2-barrier
// schedule (gR GEMM in Seg3, gZ GEMM in Seg4, sH1 double-buffered, transient
// x-prefetch inside Seg3, no gate accumulators live across barriers).
// Two barriers/step: Seg2 | B2 | Seg3 | B3 | Seg4 -> Seg2(t+1).
// Hazards: sH1w(t) Seg4-write -> B2(t+1) -> Seg3(t+1) read; sRH Seg3-write -> B3 ->
// Seg4-read -> B2(t+1) -> next write; sX Seg2-read -> B2 -> Seg3-write -> B3 ->
// Seg2(t+1) read; sH0 parity gives >=2 barriers between last-read and next-write.
__global__ __launch_bounds__(512, 2) void gru_fused(
    const float* __restrict__ x,
    const float* __restrict__ b_ih, const float* __restrict__ b_hh,
    const float* __restrict__ gate_b, const float* __restrict__ out_b,
    const f16* __restrict__ wih, const f16* __restrict__ whh,
    const f16* __restrict__ gw, const f16* __restrict__ ow,
    float* __restrict__ out)
{
    __shared__ f16 sX[ROWS][72];       // x_t tile (written for t+1 at end of Seg3)
    __shared__ f16 sH0a[ROWS][136];    // h0 double buffer
    __shared__ f16 sH0b[ROWS][136];
    __shared__ f16 sH1a[ROWS][136];    // h1 double buffer
    __shared__ f16 sH1b[ROWS][136];
    __shared__ f16 sRH[ROWS][136];     // r * h1_old

    const int tid  = threadIdx.x;
    const int lane = tid & 63;
    const int wv   = tid >> 6;      // 0..7 -> column tile
    const int p    = lane & 15;     // col-in-tile (B frag) / row-in-tile (A frag)
    const int quad = lane >> 4;     // 0..3
    const int ko   = quad * 8;      // k-offset within a K=32 chunk
    const int c    = wv * 16 + p;   // global output column 0..127
    const int row0 = blockIdx.x * ROWS;
    const bool full = (row0 + ROWS) <= TOTAL_ROWS;

    // x staging: 384 threads (waves 0..5), 8 floats each -> 48 rows x 64 floats
    const int srr = tid >> 3;          // 0..63 (only <48 used when tid<384)
    const int sf8 = (tid & 7) * 8;
    int xgr = row0 + srr;
    if (xgr > TOTAL_ROWS - 1) xgr = TOTAL_ROWS - 1;   // clamp for partial last block
    const float* xsrc = x + (size_t)xgr * (T_STEPS * F_IN) + sf8;

    // zero-init state buffers read at t=0
    for (int i = tid; i < (ROWS * 136) / 2; i += 512) {
        ((unsigned int*)&sH0a[0][0])[i] = 0u;
        ((unsigned int*)&sH1a[0][0])[i] = 0u;
    }

    // per-column biases
    const float bR  = b_ih[c] + b_hh[c];
    const float bZ  = b_ih[128 + c] + b_hh[128 + c];
    const float bIN = b_ih[256 + c];
    const float bHN = b_hh[256 + c];
    const float bGR = gate_b[c];
    const float bGZ = gate_b[128 + c];
    const float bO  = out_b[c];

    // ---- weight-stationary B fragments, ALL persistent (n = c, k = kc*32+quad*8+j) ----
    half8 Wih[3][2], Whh[3][4], Wgw[2][8], Wow[8];
    #pragma unroll
    for (int g = 0; g < 3; ++g) {
        #pragma unroll
        for (int kc = 0; kc < 2; ++kc)
            Wih[g][kc] = *(const half8*)(wih + (size_t)(g * 128 + c) * 64 + kc * 32 + ko);
        #pragma unroll
        for (int kc = 0; kc < 4; ++kc)
            Whh[g][kc] = *(const half8*)(whh + (size_t)(g * 128 + c) * 128 + kc * 32 + ko);
    }
    #pragma unroll
    for (int g = 0; g < 2; ++g)
        #pragma unroll
        for (int kc = 0; kc < 8; ++kc)
            Wgw[g][kc] = *(const half8*)(gw + (size_t)(g * 128 + c) * 256 + kc * 32 + ko);
    #pragma unroll
    for (int kc = 0; kc < 8; ++kc)
        Wow[kc] = *(const half8*)(ow + (size_t)c * 256 + kc * 32 + ko);

    // recurrent state, fp32 regs: element i -> row rt*16 + quad*4 + i, col c
    floatx4 h0p[NRT], h1p[NRT];
    #pragma unroll
    for (int rt = 0; rt < NRT; ++rt) {
        h0p[rt] = (floatx4){0.f, 0.f, 0.f, 0.f};
        h1p[rt] = (floatx4){0.f, 0.f, 0.f, 0.f};
    }

    // stage x(t=0)
    if (tid < 384) {
        const floatx4 v0 = *(const floatx4*)(xsrc);
        const floatx4 v1 = *(const floatx4*)(xsrc + 4);
        half8 h;
        h[0] = (f16)v0[0]; h[1] = (f16)v0[1]; h[2] = (f16)v0[2]; h[3] = (f16)v0[3];
        h[4] = (f16)v1[0]; h[5] = (f16)v1[1]; h[6] = (f16)v1[2]; h[7] = (f16)v1[3];
        *(half8*)&sX[srr][sf8] = h;
    }
    __syncthreads();

    for (int t = 0; t < T_STEPS; ++t) {
        const f16 (*sH0r)[136] = (t & 1) ? sH0b : sH0a;  // old h0
        f16 (*sH0w)[136]       = (t & 1) ? sH0a : sH0b;  // new h0
        const f16 (*sH1r)[136] = (t & 1) ? sH1b : sH1a;  // old h1
        f16 (*sH1w)[136]       = (t & 1) ? sH1a : sH1b;  // new h1

        // ---- Seg2: layer-0 GRUCell ----
        #pragma unroll
        for (int rt = 0; rt < NRT; ++rt) {
            floatx4 aR = (floatx4){0.f, 0.f, 0.f, 0.f};
            floatx4 aZ = aR, aIN = aR, aHN = aR;
            #pragma unroll
            for (int kc = 0; kc < 2; ++kc) {
                const half8 ax = *(const half8*)&sX[rt * 16 + p][kc * 32 + ko];
                MFMA16(aR,  ax, Wih[0][kc]);
                MFMA16(aZ,  ax, Wih[1][kc]);
                MFMA16(aIN, ax, Wih[2][kc]);
            }
            #pragma unroll
            for (int kc = 0; kc < 4; ++kc) {
                const half8 ah = *(const half8*)&sH0r[rt * 16 + p][kc * 32 + ko];
                MFMA16(aR,  ah, Whh[0][kc]);
                MFMA16(aZ,  ah, Whh[1][kc]);
                MFMA16(aHN, ah, Whh[2][kc]);
            }
            #pragma unroll
            for (int i = 0; i < 4; ++i) {
                const float r  = sigm(aR[i] + bR);
                const float z  = sigm(aZ[i] + bZ);
                const float n  = tanh_(aIN[i] + bIN + r * (aHN[i] + bHN));
                const float h0 = n + z * (h0p[rt][i] - n);
                h0p[rt][i] = h0;
                sH0w[rt * 16 + quad * 4 + i][c] = (f16)h0;
            }
        }
        __syncthreads();   // B2: h0new visible; orders Seg4(t-1) sH1w-writes vs Seg3 reads
                           //     and Seg4(t-1) sRH-reads vs Seg3 writes

        // ---- Seg3: issue x(t+1) loads; gR GEMM; write sRH; store x(t+1) -> sX ----
        floatx4 px0, px1;
        if (t < T_STEPS - 1 && tid < 384) {
            px0 = *(const floatx4*)(xsrc + (t + 1) * F_IN);
            px1 = *(const floatx4*)(xsrc + (t + 1) * F_IN + 4);
        }
        #pragma unroll
        for (int rt = 0; rt < NRT; ++rt) {
            floatx4 gR = (floatx4){0.f, 0.f, 0.f, 0.f};
            #pragma unroll
            for (int kc = 0; kc < 4; ++kc) {
                const half8 a1 = *(const half8*)&sH1r[rt * 16 + p][kc * 32 + ko];
                MFMA16(gR, a1, Wgw[0][4 + kc]);
            }
            #pragma unroll
            for (int kc = 0; kc < 4; ++kc) {
                const half8 a0 = *(const half8*)&sH0w[rt * 16 + p][kc * 32 + ko];
                MFMA16(gR, a0, Wgw[0][kc]);
            }
            #pragma unroll
            for (int i = 0; i < 4; ++i) {
                const float r1 = sigm(gR[i] + bGR);
                sRH[rt * 16 + quad * 4 + i][c] = (f16)(r1 * h1p[rt][i]);
            }
        }
        if (t < T_STEPS - 1 && tid < 384) {
            half8 h;
            h[0] = (f16)px0[0]; h[1] = (f16)px0[1]; h[2] = (f16)px0[2]; h[3] = (f16)px0[3];
            h[4] = (f16)px1[0]; h[5] = (f16)px1[1]; h[6] = (f16)px1[2]; h[7] = (f16)px1[3];
            *(half8*)&sX[srr][sf8] = h;
        }
        __syncthreads();   // B3: sRH and sX(t+1) visible

        // ---- Seg4: gZ GEMM (old h1) + candidate GEMM + h1 update + output ----
        #pragma unroll
        for (int rt = 0; rt < NRT; ++rt) {
            floatx4 gZ = (floatx4){0.f, 0.f, 0.f, 0.f};
            floatx4 aC = gZ;
            #pragma unroll
            for (int kc = 0; kc < 4; ++kc) {
                const half8 a1 = *(const half8*)&sH1r[rt * 16 + p][kc * 32 + ko];
                MFMA16(gZ, a1, Wgw[1][4 + kc]);
            }
            #pragma unroll
            for (int kc = 0; kc < 4; ++kc) {
                const half8 a0 = *(const half8*)&sH0w[rt * 16 + p][kc * 32 + ko];
                MFMA16(gZ, a0, Wgw[1][kc]);
                MFMA16(aC, a0, Wow[kc]);
            }
            #pragma unroll
            for (int kc = 0; kc < 4; ++kc) {
                const half8 ar = *(const half8*)&sRH[rt * 16 + p][kc * 32 + ko];
                MFMA16(aC, ar, Wow[4 + kc]);
            }
            #pragma unroll
            for (int i = 0; i < 4; ++i) {
                const float zz = sigm(gZ[i] + bGZ);
                const float cd = tanh_(aC[i] + bO);
                const float hv = cd + zz * (h1p[rt][i] - cd);
                h1p[rt][i] = hv;
                sH1w[rt * 16 + quad * 4 + i][c] = (f16)hv;
                const int grow = row0 + rt * 16 + quad * 4 + i;
                if (full || grow < TOTAL_ROWS)
                    out[((size_t)grow * T_STEPS + t) * H_DIM + c] = hv;
            }
        }
        // no trailing barrier: B2(t+1) orders Seg4 writes/reads vs next step
    }
}

extern "C" void kernel_launch(void* const* d_in, const int* in_sizes, int n_in,
                              void* d_out, int out_size, void* d_ws, size_t ws_size,
                              hipStream_t stream) {
    (void)in_sizes; (void)n_in; (void)out_size; (void)ws_size;
    const float* x      = (const float*)d_in[0];
    const float* w_ih   = (const float*)d_in[1];
    const float* w_hh   = (const float*)d_in[2];
    const float* b_ih   = (const float*)d_in[3];
    const float* b_hh   = (const float*)d_in[4];
    const float* gate_w = (const float*)d_in[5];
    const float* gate_b = (const float*)d_in[6];
    const float* out_w  = (const float*)d_in[7];
    const float* out_b  = (const float*)d_in[8];

    f16* wsH = (f16*)d_ws;
    f16* wih = wsH;                 // 384*64   = 24576 halves
    f16* whh = wsH + 24576;         // 384*128  = 49152
    f16* gw  = wsH + 73728;         // 256*256  = 65536
    f16* ow  = wsH + 139264;        // 128*256  = 32768

    cvt_f32_f16<<<(24576 + 255) / 256, 256, 0, stream>>>(w_ih, wih, 24576);
    cvt_f32_f16<<<(49152 + 255) / 256, 256, 0, stream>>>(w_hh, whh, 49152);
    cvt_f32_f16<<<(65536 + 255) / 256, 256, 0, stream>>>(gate_w, gw, 65536);
    cvt_f32_f16<<<(32768 + 255) / 256, 256, 0, stream>>>(out_w, ow, 32768);

    gru_fused<<<NUM_BLOCKS, 512, 0, stream>>>(x, b_ih, b_hh, gate_b, out_b,
                                              wih, whh, gw, ow, (float*)d_out);
}